// Round 10
// baseline (228.497 us; speedup 1.0000x reference)
//
#include <hip/hip_runtime.h>

// Problem: inputs (4096, 8192) f32.
// out[i][j] = max over s in {0,2048,4096,6144} of in[i][(j-s) mod 8192]
//           = max_k in[i][(j mod 2048) + 2048*k],  k=0..3
// => compute 2048-wide per-row max of the 4 column quarters, write it 4x.
//
// R3 lesson: write amplification (235 vs 134 MB) came from stride-2 lane
// layout (partial 32B granules to HBM), not provably from nt-stores.
// R5 experiment: coalesced layout (identical to R4) + nt-stores only.
// Full 128B lines per wave-store => no partial granules; writes bypass L2,
// leaving cache for the (L3-hot) input stream.

#define ROWS 4096u
#define L    8192u
#define Q    2048u         // L/4
#define QV   (Q / 4u)      // 512 float4 per quarter-row

typedef float f32x4 __attribute__((ext_vector_type(4)));

__global__ __launch_bounds__(256) void dense_max_pool_kernel(
    const float* __restrict__ in, float* __restrict__ out) {
    // one thread per float4 of the reduced vector: ROWS * QV threads (2M)
    unsigned idx = blockIdx.x * blockDim.x + threadIdx.x;
    unsigned row = idx >> 9;          // / QV (512)
    unsigned q   = idx & (QV - 1u);   // % QV

    const f32x4* in4  = (const f32x4*)in;
    f32x4*       out4 = (f32x4*)out;

    unsigned base = row * (L / 4u) + q;   // float4 index; max < 2^23, fits u32

    f32x4 a = in4[base];
    f32x4 b = in4[base + QV];
    f32x4 c = in4[base + 2u * QV];
    f32x4 d = in4[base + 3u * QV];

    f32x4 m;
    m.x = fmaxf(fmaxf(a.x, b.x), fmaxf(c.x, d.x));
    m.y = fmaxf(fmaxf(a.y, b.y), fmaxf(c.y, d.y));
    m.z = fmaxf(fmaxf(a.z, b.z), fmaxf(c.z, d.z));
    m.w = fmaxf(fmaxf(a.w, b.w), fmaxf(c.w, d.w));

    __builtin_nontemporal_store(m, &out4[base]);
    __builtin_nontemporal_store(m, &out4[base + QV]);
    __builtin_nontemporal_store(m, &out4[base + 2u * QV]);
    __builtin_nontemporal_store(m, &out4[base + 3u * QV]);
}

extern "C" void kernel_launch(void* const* d_in, const int* in_sizes, int n_in,
                              void* d_out, int out_size, void* d_ws, size_t ws_size,
                              hipStream_t stream) {
    const float* in = (const float*)d_in[0];
    float* out = (float*)d_out;

    const unsigned total_threads = ROWS * QV;    // 2,097,152
    const unsigned block = 256;
    const unsigned grid = total_threads / block; // 8192

    dense_max_pool_kernel<<<grid, block, 0, stream>>>(in, out);
}